// Round 17
// baseline (218.160 us; speedup 1.0000x reference)
//
#include <hip/hip_runtime.h>

typedef _Float16 half8 __attribute__((ext_vector_type(8)));
typedef _Float16 half4 __attribute__((ext_vector_type(4)));
typedef float f32x4 __attribute__((ext_vector_type(4)));

__device__ inline unsigned short f2h(float f) {
  union { _Float16 h; unsigned short u; } cv;
  cv.h = (_Float16)f;
  return cv.u;
}

__device__ inline unsigned int pk2(float a, float b) {
  return __builtin_bit_cast(unsigned int, __builtin_amdgcn_cvt_pkrtz(a, b));
}

// ---- prep: fused weight fp32->fp16 (blocks 0..3071) + GN partial stats ----
__global__ __launch_bounds__(256) void prep(const float* __restrict__ wqkv,
                                            const float* __restrict__ wproj,
                                            _Float16* __restrict__ wq,
                                            _Float16* __restrict__ wp,
                                            const float* __restrict__ x,
                                            float* __restrict__ mr) {
  if (blockIdx.x < 3072) {
    const int i = blockIdx.x * 256 + threadIdx.x;  // covers 786432 exactly
    wq[i] = (_Float16)wqkv[i];
    if (i < 262144) wp[i] = (_Float16)wproj[i];
    return;
  }
  const int sb = blockIdx.x - 3072;  // 0..255, one per (b,g,half-slab)
  const float4* xv = (const float4*)(x + (size_t)sb * 32768);
  float s = 0.f, s2 = 0.f;
  for (int i = threadIdx.x; i < 8192; i += 256) {
    float4 v = xv[i];
    s += v.x + v.y + v.z + v.w;
    s2 += v.x * v.x + v.y * v.y + v.z * v.z + v.w * v.w;
  }
  for (int m = 32; m; m >>= 1) {
    s += __shfl_down(s, m);
    s2 += __shfl_down(s2, m);
  }
  __shared__ float ls[4], ls2[4];
  const int wid = threadIdx.x >> 6;
  if ((threadIdx.x & 63) == 0) { ls[wid] = s; ls2[wid] = s2; }
  __syncthreads();
  if (threadIdx.x == 0) {
    mr[sb * 2] = ls[0] + ls[1] + ls[2] + ls[3];
    mr[sb * 2 + 1] = ls2[0] + ls2[1] + ls2[2] + ls2[3];
  }
}

// ------- GN apply + transpose: x[b,c,p] -> hn[b,p,c] fp16 (c contiguous) -------
__global__ __launch_bounds__(256) void gn_apply(const float* __restrict__ x,
                                                const float* __restrict__ mr,
                                                const float* __restrict__ sc,
                                                const float* __restrict__ bi,
                                                _Float16* __restrict__ hn) {
  __shared__ __align__(16) _Float16 t[64][72];  // 64p x 64c tile, padded rows
  const int b = blockIdx.z, cb = blockIdx.y, pb = blockIdx.x;
  const int c0 = cb * 64, p0 = pb * 64;
  const int bg = b * 8 + cb;  // group == cb (64 ch per group)
  const float S = mr[bg * 4 + 0] + mr[bg * 4 + 2];
  const float S2 = mr[bg * 4 + 1] + mr[bg * 4 + 3];
  const float mean = S * (1.f / 65536.f);
  const float var = S2 * (1.f / 65536.f) - mean * mean;
  const float rstd = rsqrtf(var + 1e-5f);
  const int tp = threadIdx.x & 63;
  const int tc = threadIdx.x >> 6;
#pragma unroll
  for (int i = 0; i < 16; i++) {
    const int c = tc * 16 + i;
    const float g = sc[c0 + c] * rstd;
    const float v = x[((size_t)b * 512 + c0 + c) * 1024 + p0 + tp];
    t[tp][c] = (_Float16)((v - mean) * g + bi[c0 + c]);
  }
  __syncthreads();
  const int wp = threadIdx.x >> 2;
  const int wc = (threadIdx.x & 3) * 16;
  _Float16* dst = hn + ((size_t)b * 1024 + p0 + wp) * 512 + c0 + wc;
  *(uint4*)dst = *(const uint4*)&t[wp][wc];
  *(uint4*)(dst + 8) = *(const uint4*)&t[wp][wc + 8];
}

// ---- MFMA GEMM: C[o,p] = sum_c A[o,c]*Bt[p,c], 128x128x64 tiles, 8 waves ----
// Reg-staged prefetch (T14, proven in attn R4): tile k+1 loaded into VGPRs at
// the top of step k (loads-to-regs are NOT drained by the barrier), written to
// LDS after the compute barrier. Single 32 KB LDS buffer.
// EPI=0: qkv epilogue (bias, split into q[b,h,p,d](*0.125*log2e), k, v[b,h,d,p])
// EPI=1: proj epilogue (bias + residual, fp32 out [b,c,p])
template <int EPI>
__global__ __launch_bounds__(512, 4) void gemm_mfma(
    const _Float16* __restrict__ A, const _Float16* __restrict__ Bt,
    const float* __restrict__ bias, const float* __restrict__ xin,
    float* __restrict__ fout, _Float16* __restrict__ qo,
    _Float16* __restrict__ ko, _Float16* __restrict__ vo) {
  __shared__ __align__(16) _Float16 As[128 * 64];
  __shared__ __align__(16) _Float16 Bs[128 * 64];
  const int b = blockIdx.z;
  const int m0 = blockIdx.y * 128, n0 = blockIdx.x * 128;
  const char* Ab = (const char*)A;
  const char* Bb = (const char*)(Bt + (size_t)b * 1024 * 512);
  const int t = threadIdx.x, lane = t & 63, w = t >> 6;
  const int wm = (w & 1) * 64, wn = (w >> 1) * 32;  // 2x4 grid of 64x32
  const int lr = lane & 15, lk = lane >> 4;
  // staging map: 512 threads x 2 chunks of 16B cover each 16 KB tile.
  // linear global source; swizzled LDS dest (write-swz == read-swz, rule #21)
  int srow[2], scol[2], sdst[2];
#pragma unroll
  for (int it = 0; it < 2; it++) {
    const int flat = it * 512 + t;
    srow[it] = flat >> 3;
    scol[it] = (flat & 7) * 16;
    sdst[it] = srow[it] * 128 + (scol[it] ^ ((srow[it] & 7) << 4));
  }
  f32x4 acc[4][2] = {};
  // prologue: stage tile 0 (regs -> LDS)
  {
    uint4 a0[2], b0[2];
#pragma unroll
    for (int it = 0; it < 2; it++) {
      a0[it] = *(const uint4*)(Ab + (size_t)(m0 + srow[it]) * 1024 + scol[it]);
      b0[it] = *(const uint4*)(Bb + (size_t)(n0 + srow[it]) * 1024 + scol[it]);
    }
#pragma unroll
    for (int it = 0; it < 2; it++) {
      *(uint4*)((char*)As + sdst[it]) = a0[it];
      *(uint4*)((char*)Bs + sdst[it]) = b0[it];
    }
  }
  __syncthreads();
#pragma unroll 1
  for (int k0 = 0; k0 < 512; k0 += 64) {
    // T14 issue-early: next tile -> registers, in flight during compute
    uint4 an[2], bn[2];
    if (k0 < 448) {
#pragma unroll
      for (int it = 0; it < 2; it++) {
        an[it] = *(const uint4*)(Ab + (size_t)(m0 + srow[it]) * 1024 +
                                 (k0 + 64) * 2 + scol[it]);
        bn[it] = *(const uint4*)(Bb + (size_t)(n0 + srow[it]) * 1024 +
                                 (k0 + 64) * 2 + scol[it]);
      }
    }
    // compute on current LDS tile
#pragma unroll
    for (int kk = 0; kk < 2; kk++) {
      half8 af[4], bf[2];
#pragma unroll
      for (int i = 0; i < 4; i++) {
        const int ra = wm + i * 16 + lr;
        af[i] = *(const half8*)((const char*)As +
                                ((ra * 128 + kk * 64 + lk * 16) ^ ((ra & 7) << 4)));
      }
#pragma unroll
      for (int j = 0; j < 2; j++) {
        const int rb = wn + j * 16 + lr;
        bf[j] = *(const half8*)((const char*)Bs +
                                ((rb * 128 + kk * 64 + lk * 16) ^ ((rb & 7) << 4)));
      }
#pragma unroll
      for (int i = 0; i < 4; i++)
#pragma unroll
        for (int j = 0; j < 2; j++)
          acc[i][j] = __builtin_amdgcn_mfma_f32_16x16x32_f16(af[i], bf[j],
                                                             acc[i][j], 0, 0, 0);
    }
    __syncthreads();  // all waves done reading current tile
    if (k0 < 448) {
#pragma unroll
      for (int it = 0; it < 2; it++) {
        *(uint4*)((char*)As + sdst[it]) = an[it];
        *(uint4*)((char*)Bs + sdst[it]) = bn[it];
      }
    }
    __syncthreads();  // staged writes visible
  }
#pragma unroll
  for (int i = 0; i < 4; i++) {
    const int o = m0 + wm + i * 16 + lk * 4;  // 4 consecutive rows o..o+3
#pragma unroll
    for (int j = 0; j < 2; j++) {
      const int p = n0 + wn + j * 16 + lr;
      float vv[4];
#pragma unroll
      for (int r = 0; r < 4; r++) vv[r] = acc[i][j][r] + bias[o + r];
      if (EPI == 0) {
        const int sec = o >> 9, oc = o & 511;
        const int h = oc >> 6, d0 = oc & 63;
        if (sec == 0) {  // Q, pre-scaled by 1/sqrt(64) * log2(e)
          const float qs = 0.125f * 1.44269504f;
          ushort4 pk;
          pk.x = f2h(vv[0] * qs); pk.y = f2h(vv[1] * qs);
          pk.z = f2h(vv[2] * qs); pk.w = f2h(vv[3] * qs);
          *(ushort4*)(qo + ((size_t)(b * 8 + h) * 1024 + p) * 64 + d0) = pk;
        } else if (sec == 1) {  // K
          ushort4 pk;
          pk.x = f2h(vv[0]); pk.y = f2h(vv[1]);
          pk.z = f2h(vv[2]); pk.w = f2h(vv[3]);
          *(ushort4*)(ko + ((size_t)(b * 8 + h) * 1024 + p) * 64 + d0) = pk;
        } else {  // V, transposed to [d, p]
#pragma unroll
          for (int r = 0; r < 4; r++)
            vo[((size_t)(b * 8 + h) * 64 + d0 + r) * 1024 + p] = (_Float16)vv[r];
        }
      } else {
        const size_t idx = ((size_t)b * 512 + o) * 1024 + p;
#pragma unroll
        for (int r = 0; r < 4; r++)
          fout[idx + (size_t)r * 1024] = xin[idx + (size_t)r * 1024] + vv[r];
      }
    }
  }
}

// ---- flash attention v7s: v7r + raw v_exp_f32 + offset folded into C-init ----
// block = (b,h) x 256 q-rows (8 waves x 32); q pre-scaled by 0.125*log2e
// P = 2^(s-10) via s initialized at -10; l = sum P via MFMA
// k [b,h,p,d]; v [b,h,d,p]; o [b,p,c] fp16
__global__ __launch_bounds__(512, 4) void attn(const _Float16* __restrict__ q,
                                               const _Float16* __restrict__ k,
                                               const _Float16* __restrict__ v,
                                               _Float16* __restrict__ o) {
  __shared__ __align__(16) _Float16 KT[2][4096];  // [buf][key 64][d 64] swizzled
  __shared__ __align__(16) _Float16 VT[2][4096];  // [buf][d 64][key 64] swizzled
  __shared__ __align__(16) _Float16 PT[8][2048];  // per-wave P^T [q 32][key 64]
  // XCD-chunked: 64 consecutive flat ids (16 bh pairs) per XCD (T1)
  const int id = blockIdx.x;
  const int flat = (id & 7) * 64 + (id >> 3);
  const int qb = flat & 3, bh = flat >> 2;
  const int b = bh >> 3, h = bh & 7;
  const int t = threadIdx.x, lane = t & 63, w = t >> 6;
  const int lr = lane & 15, lk = lane >> 4;
  const int q0 = qb * 256 + w * 32;
  const _Float16* qp = q + (size_t)bh * 65536;
  const char* kc = (const char*)(k + (size_t)bh * 65536);  // [p][d] rows 128 B
  const char* vc = (const char*)(v + (size_t)bh * 65536);  // [d][p] rows 2048 B
  // staging map: thread t -> row t>>3, 16B chunk (t&7)*16 (covers 8 KB/tile)
  const int srow = t >> 3, scol = (t & 7) * 16;
  const int sdst = srow * 128 + (scol ^ ((srow & 7) << 4));
  // ---- loop-invariant swizzled LDS byte offsets ----
  int koff[4][2];
#pragma unroll
  for (int j = 0; j < 4; j++) {
    const int row = j * 16 + lr, sw = (row & 7) << 4;
    koff[j][0] = row * 128 + ((lk * 16) ^ sw);
    koff[j][1] = row * 128 + ((64 + lk * 16) ^ sw);
  }
  int pwoff[2][4];  // P-write: q-row g*16+lr, key group j
#pragma unroll
  for (int g = 0; g < 2; g++) {
    const int qhat = g * 16 + lr, sw = (qhat & 7) << 4;
#pragma unroll
    for (int j = 0; j < 4; j++)
      pwoff[g][j] = qhat * 128 + ((j * 32 + lk * 8) ^ sw);
  }
  // Q fragments
  half8 qf[2][2];
#pragma unroll
  for (int g = 0; g < 2; g++)
#pragma unroll
    for (int kk = 0; kk < 2; kk++)
      qf[g][kk] = *(const half8*)(qp + (q0 + g * 16 + lr) * 64 + kk * 32 + lk * 8);
  const half8 onesv = {(_Float16)1.f, (_Float16)1.f, (_Float16)1.f, (_Float16)1.f,
                       (_Float16)1.f, (_Float16)1.f, (_Float16)1.f, (_Float16)1.f};
  // prologue: stage tile 0
  {
    uint4 k0 = *(const uint4*)(kc + srow * 128 + scol);
    uint4 v0 = *(const uint4*)(vc + srow * 2048 + scol);
    *(uint4*)((char*)KT + sdst) = k0;
    *(uint4*)((char*)VT + sdst) = v0;
  }
  __syncthreads();
  f32x4 aco[2][4] = {};
  f32x4 lacc[2] = {};  // row-sum of P via MFMA(P, ones); PV-accumulator layout
  char* Pc = (char*)PT + w * 4096;
#pragma unroll 1
  for (int kt = 0; kt < 16; kt++) {
    const int cur = kt & 1;
    const char* Kc = (const char*)KT + cur * 8192;
    const char* Vc = (const char*)VT + cur * 8192;
    // T14 issue-early: next tile global loads in flight during compute
    uint4 kn, vn;
    if (kt < 15) {
      kn = *(const uint4*)(kc + (kt + 1) * 8192 + srow * 128 + scol);
      vn = *(const uint4*)(vc + srow * 2048 + (kt + 1) * 128 + scol);
    }
    // ---- QK^T swapped, C-init = -10 (softmax offset folded in) ----
    f32x4 s[2][4];
#pragma unroll
    for (int g = 0; g < 2; g++)
#pragma unroll
      for (int j = 0; j < 4; j++) {
        s[g][j][0] = -10.f; s[g][j][1] = -10.f;
        s[g][j][2] = -10.f; s[g][j][3] = -10.f;
      }
    __builtin_amdgcn_s_setprio(1);
#pragma unroll
    for (int j = 0; j < 4; j++) {
      const half8 kf0 = *(const half8*)(Kc + koff[j][0]);
      const half8 kf1 = *(const half8*)(Kc + koff[j][1]);
#pragma unroll
      for (int g = 0; g < 2; g++) {
        s[g][j] = __builtin_amdgcn_mfma_f32_16x16x32_f16(kf0, qf[g][0], s[g][j], 0, 0, 0);
        s[g][j] = __builtin_amdgcn_mfma_f32_16x16x32_f16(kf1, qf[g][1], s[g][j], 0, 0, 0);
      }
    }
    __builtin_amdgcn_s_setprio(0);
    // ---- P = 2^s via raw v_exp_f32, packed store to fp16 LDS tile ----
#pragma unroll
    for (int g = 0; g < 2; g++) {
#pragma unroll
      for (int j = 0; j < 4; j++) {
        uint2 pw;
        pw.x = pk2(__builtin_amdgcn_exp2f(s[g][j][0]),
                   __builtin_amdgcn_exp2f(s[g][j][1]));
        pw.y = pk2(__builtin_amdgcn_exp2f(s[g][j][2]),
                   __builtin_amdgcn_exp2f(s[g][j][3]));
        *(uint2*)(Pc + pwoff[g][j]) = pw;
      }
    }
    // ---- PV: O += P^T * V^T ; l-sum via MFMA(P, ones) ----
    __builtin_amdgcn_s_setprio(1);
#pragma unroll
    for (int kk = 0; kk < 2; kk++) {
      half8 vf[4];
#pragma unroll
      for (int jd = 0; jd < 4; jd++)
        vf[jd] = *(const half8*)(Vc + koff[jd][kk]);
#pragma unroll
      for (int g = 0; g < 2; g++) {
        const half8 pf = *(const half8*)(Pc + koff[g][kk]);
        lacc[g] = __builtin_amdgcn_mfma_f32_16x16x32_f16(pf, onesv, lacc[g], 0, 0, 0);
#pragma unroll
        for (int jd = 0; jd < 4; jd++)
          aco[g][jd] = __builtin_amdgcn_mfma_f32_16x16x32_f16(pf, vf[jd], aco[g][jd], 0, 0, 0);
      }
    }
    __builtin_amdgcn_s_setprio(0);
    // ---- write staged tile, flip buffers ----
    if (kt < 15) {
      *(uint4*)((char*)KT + (cur ^ 1) * 8192 + sdst) = kn;
      *(uint4*)((char*)VT + (cur ^ 1) * 8192 + sdst) = vn;
    }
    __syncthreads();
  }
  // ---- epilogue: divide by l (already in PV layout), store [b,p,c] ----
#pragma unroll
  for (int g = 0; g < 2; g++)
#pragma unroll
    for (int r = 0; r < 4; r++) {
      const float rl = 1.f / lacc[g][r];
      const int row = q0 + g * 16 + 4 * lk + r;
#pragma unroll
      for (int jd = 0; jd < 4; jd++)
        o[((size_t)b * 1024 + row) * 512 + h * 64 + jd * 16 + lr] =
            (_Float16)(aco[g][jd][r] * rl);
    }
}

extern "C" void kernel_launch(void* const* d_in, const int* in_sizes, int n_in,
                              void* d_out, int out_size, void* d_ws, size_t ws_size,
                              hipStream_t stream) {
  const float* x = (const float*)d_in[0];
  const float* gsc = (const float*)d_in[1];
  const float* gbi = (const float*)d_in[2];
  const float* wqkv = (const float*)d_in[3];
  const float* bqkv = (const float*)d_in[4];
  const float* wproj = (const float*)d_in[5];
  const float* bproj = (const float*)d_in[6];
  float* out = (float*)d_out;
  char* ws = (char*)d_ws;
  // workspace layout (bytes)
  float* mr = (float*)ws;                                 // 256*2*4   = 2 KB
  _Float16* wq16 = (_Float16*)(ws + 4096);                // 1536*512*2
  _Float16* wp16 = (_Float16*)(ws + 4096 + 1572864);      // 512*512*2
  _Float16* hn = (_Float16*)(ws + 2101248);               // 16*1024*512*2 (reused for attn out)
  _Float16* q16 = (_Float16*)(ws + 18878464);             // 16*8*1024*64*2
  _Float16* k16 = (_Float16*)(ws + 35655680);
  _Float16* v16 = (_Float16*)(ws + 52432896);             // end ~66 MB

  hipLaunchKernelGGL(prep, dim3(3328), dim3(256), 0, stream, wqkv, wproj, wq16,
                     wp16, x, mr);
  hipLaunchKernelGGL(gn_apply, dim3(16, 8, 16), dim3(256), 0, stream, x, mr, gsc,
                     gbi, hn);
  hipLaunchKernelGGL((gemm_mfma<0>), dim3(8, 12, 16), dim3(512), 0, stream, wq16,
                     hn, bqkv, (const float*)nullptr, (float*)nullptr, q16, k16,
                     v16);
  hipLaunchKernelGGL(attn, dim3(512), dim3(512), 0, stream, q16, k16, v16, hn);
  hipLaunchKernelGGL((gemm_mfma<1>), dim3(8, 4, 16), dim3(512), 0, stream, wp16,
                     hn, bproj, x, out, (_Float16*)nullptr, (_Float16*)nullptr,
                     (_Float16*)nullptr);
}

// Round 18
// 127.985 us; speedup vs baseline: 1.7046x; 1.7046x over previous
//
#include <hip/hip_runtime.h>

typedef _Float16 half8 __attribute__((ext_vector_type(8)));
typedef _Float16 half4 __attribute__((ext_vector_type(4)));
typedef float f32x4 __attribute__((ext_vector_type(4)));

__device__ inline unsigned short f2h(float f) {
  union { _Float16 h; unsigned short u; } cv;
  cv.h = (_Float16)f;
  return cv.u;
}

__device__ inline unsigned int pk2(float a, float b) {
  return __builtin_bit_cast(unsigned int, __builtin_amdgcn_cvt_pkrtz(a, b));
}

// async global->LDS, 16B per lane; LDS dest is wave-uniform base + lane*16
__device__ inline void gload_lds16(const void* g, void* l) {
  __builtin_amdgcn_global_load_lds(
      (const __attribute__((address_space(1))) void*)g,
      (__attribute__((address_space(3))) void*)l, 16, 0, 0);
}

// ---- prep: weights fp32->fp16 via float4 (blocks 0..767) + GN partial stats ----
__global__ __launch_bounds__(256) void prep(const float* __restrict__ wqkv,
                                            const float* __restrict__ wproj,
                                            _Float16* __restrict__ wq,
                                            _Float16* __restrict__ wp,
                                            const float* __restrict__ x,
                                            float* __restrict__ mr) {
  if (blockIdx.x < 768) {
    const int i = blockIdx.x * 256 + threadIdx.x;  // float4 idx, covers 196608
    const float4 v = ((const float4*)wqkv)[i];
    ushort4 pk;
    pk.x = f2h(v.x); pk.y = f2h(v.y); pk.z = f2h(v.z); pk.w = f2h(v.w);
    *(ushort4*)(wq + (size_t)i * 4) = pk;
    if (i < 65536) {
      const float4 u = ((const float4*)wproj)[i];
      ushort4 pu;
      pu.x = f2h(u.x); pu.y = f2h(u.y); pu.z = f2h(u.z); pu.w = f2h(u.w);
      *(ushort4*)(wp + (size_t)i * 4) = pu;
    }
    return;
  }
  const int sb = blockIdx.x - 768;  // 0..255, one per (b,g,half-slab)
  const float4* xv = (const float4*)(x + (size_t)sb * 32768);
  float s = 0.f, s2 = 0.f;
  for (int i = threadIdx.x; i < 8192; i += 256) {
    float4 v = xv[i];
    s += v.x + v.y + v.z + v.w;
    s2 += v.x * v.x + v.y * v.y + v.z * v.z + v.w * v.w;
  }
  for (int m = 32; m; m >>= 1) {
    s += __shfl_down(s, m);
    s2 += __shfl_down(s2, m);
  }
  __shared__ float ls[4], ls2[4];
  const int wid = threadIdx.x >> 6;
  if ((threadIdx.x & 63) == 0) { ls[wid] = s; ls2[wid] = s2; }
  __syncthreads();
  if (threadIdx.x == 0) {
    mr[sb * 2] = ls[0] + ls[1] + ls[2] + ls[3];
    mr[sb * 2 + 1] = ls2[0] + ls2[1] + ls2[2] + ls2[3];
  }
}

// ------- GN apply + transpose: x[b,c,p] -> hn[b,p,c] fp16 (c contiguous) -------
__global__ __launch_bounds__(256) void gn_apply(const float* __restrict__ x,
                                                const float* __restrict__ mr,
                                                const float* __restrict__ sc,
                                                const float* __restrict__ bi,
                                                _Float16* __restrict__ hn) {
  __shared__ __align__(16) _Float16 t[64][72];  // 64p x 64c tile, padded rows
  const int b = blockIdx.z, cb = blockIdx.y, pb = blockIdx.x;
  const int c0 = cb * 64, p0 = pb * 64;
  const int bg = b * 8 + cb;  // group == cb (64 ch per group)
  const float S = mr[bg * 4 + 0] + mr[bg * 4 + 2];
  const float S2 = mr[bg * 4 + 1] + mr[bg * 4 + 3];
  const float mean = S * (1.f / 65536.f);
  const float var = S2 * (1.f / 65536.f) - mean * mean;
  const float rstd = rsqrtf(var + 1e-5f);
  const int tp = threadIdx.x & 63;
  const int tc = threadIdx.x >> 6;
#pragma unroll
  for (int i = 0; i < 16; i++) {
    const int c = tc * 16 + i;
    const float g = sc[c0 + c] * rstd;
    const float v = x[((size_t)b * 512 + c0 + c) * 1024 + p0 + tp];
    t[tp][c] = (_Float16)((v - mean) * g + bi[c0 + c]);
  }
  __syncthreads();
  const int wp = threadIdx.x >> 2;
  const int wc = (threadIdx.x & 3) * 16;
  _Float16* dst = hn + ((size_t)b * 1024 + p0 + wp) * 512 + c0 + wc;
  *(uint4*)dst = *(const uint4*)&t[wp][wc];
  *(uint4*)(dst + 8) = *(const uint4*)&t[wp][wc + 8];
}

// ---- MFMA GEMM: C[o,p] = sum_c A[o,c]*Bt[p,c], 128x128x64 tiles, 8 waves ----
// 512 threads; each wave computes a 64x32 subtile (acc = 8 f32x4 = 32 AGPR)
// staging via global_load_lds (linear LDS dest, pre-unswizzled source)
// EPI=0: qkv epilogue (bias, split into q[b,h,p,d](*0.125*log2e), k, v[b,h,d,p])
// EPI=1: proj epilogue (bias + residual, fp32 out [b,c,p])
template <int EPI>
__global__ __launch_bounds__(512, 4) void gemm_mfma(
    const _Float16* __restrict__ A, const _Float16* __restrict__ Bt,
    const float* __restrict__ bias, const float* __restrict__ xin,
    float* __restrict__ fout, _Float16* __restrict__ qo,
    _Float16* __restrict__ ko, _Float16* __restrict__ vo) {
  __shared__ __align__(16) _Float16 As[128 * 64];
  __shared__ __align__(16) _Float16 Bs[128 * 64];
  const int b = blockIdx.z;
  const int m0 = blockIdx.y * 128, n0 = blockIdx.x * 128;
  const char* Ab = (const char*)A;
  const char* Bb = (const char*)(Bt + (size_t)b * 1024 * 512);
  const int t = threadIdx.x, lane = t & 63, w = t >> 6;
  const int wm = (w & 1) * 64, wn = (w >> 1) * 32;  // 2x4 grid of 64x32
  const int lr = lane & 15, lk = lane >> 4;
  // staging: 512 threads x 2 chunks of 16B cover each 16 KB tile
  int srow[2], scb[2];
#pragma unroll
  for (int it = 0; it < 2; it++) {
    srow[it] = it * 64 + (t >> 3);
    scb[it] = ((t & 7) * 16) ^ ((srow[it] & 7) << 4);
  }
  f32x4 acc[4][2] = {};
#pragma unroll 1
  for (int k0 = 0; k0 < 512; k0 += 64) {
#pragma unroll
    for (int it = 0; it < 2; it++) {
      const size_t go = (size_t)(m0 + srow[it]) * 1024 + k0 * 2 + scb[it];
      const size_t gob = (size_t)(n0 + srow[it]) * 1024 + k0 * 2 + scb[it];
      gload_lds16(Ab + go, (char*)As + it * 8192 + w * 1024);
      gload_lds16(Bb + gob, (char*)Bs + it * 8192 + w * 1024);
    }
    __syncthreads();
#pragma unroll
    for (int kk = 0; kk < 2; kk++) {
      half8 af[4], bf[2];
#pragma unroll
      for (int i = 0; i < 4; i++) {
        const int ra = wm + i * 16 + lr;
        af[i] = *(const half8*)((const char*)As +
                                ((ra * 128 + kk * 64 + lk * 16) ^ ((ra & 7) << 4)));
      }
#pragma unroll
      for (int j = 0; j < 2; j++) {
        const int rb = wn + j * 16 + lr;
        bf[j] = *(const half8*)((const char*)Bs +
                                ((rb * 128 + kk * 64 + lk * 16) ^ ((rb & 7) << 4)));
      }
#pragma unroll
      for (int i = 0; i < 4; i++)
#pragma unroll
        for (int j = 0; j < 2; j++)
          acc[i][j] = __builtin_amdgcn_mfma_f32_16x16x32_f16(af[i], bf[j],
                                                             acc[i][j], 0, 0, 0);
    }
    __syncthreads();
  }
#pragma unroll
  for (int i = 0; i < 4; i++) {
    const int o = m0 + wm + i * 16 + lk * 4;  // 4 consecutive rows o..o+3
#pragma unroll
    for (int j = 0; j < 2; j++) {
      const int p = n0 + wn + j * 16 + lr;
      float vv[4];
#pragma unroll
      for (int r = 0; r < 4; r++) vv[r] = acc[i][j][r] + bias[o + r];
      if (EPI == 0) {
        const int sec = o >> 9, oc = o & 511;
        const int h = oc >> 6, d0 = oc & 63;
        if (sec == 0) {  // Q, pre-scaled by 1/sqrt(64) * log2(e)
          const float qs = 0.125f * 1.44269504f;
          ushort4 pk;
          pk.x = f2h(vv[0] * qs); pk.y = f2h(vv[1] * qs);
          pk.z = f2h(vv[2] * qs); pk.w = f2h(vv[3] * qs);
          *(ushort4*)(qo + ((size_t)(b * 8 + h) * 1024 + p) * 64 + d0) = pk;
        } else if (sec == 1) {  // K
          ushort4 pk;
          pk.x = f2h(vv[0]); pk.y = f2h(vv[1]);
          pk.z = f2h(vv[2]); pk.w = f2h(vv[3]);
          *(ushort4*)(ko + ((size_t)(b * 8 + h) * 1024 + p) * 64 + d0) = pk;
        } else {  // V, transposed to [d, p]
#pragma unroll
          for (int r = 0; r < 4; r++)
            vo[((size_t)(b * 8 + h) * 64 + d0 + r) * 1024 + p] = (_Float16)vv[r];
        }
      } else {
        const size_t idx = ((size_t)b * 512 + o) * 1024 + p;
#pragma unroll
        for (int r = 0; r < 4; r++)
          fout[idx + (size_t)r * 1024] = xin[idx + (size_t)r * 1024] + vv[r];
      }
    }
  }
}

// ---- flash attention v7s: fixed-offset softmax, raw v_exp_f32, MFMA l-sum ----
// block = (b,h) x 256 q-rows (8 waves x 32); q pre-scaled by 0.125*log2e
// P = 2^(s-10) via s initialized at -10; l = sum P via MFMA
// k [b,h,p,d]; v [b,h,d,p]; o [b,p,c] fp16
__global__ __launch_bounds__(512, 4) void attn(const _Float16* __restrict__ q,
                                               const _Float16* __restrict__ k,
                                               const _Float16* __restrict__ v,
                                               _Float16* __restrict__ o) {
  __shared__ __align__(16) _Float16 KT[2][4096];  // [buf][key 64][d 64] swizzled
  __shared__ __align__(16) _Float16 VT[2][4096];  // [buf][d 64][key 64] swizzled
  __shared__ __align__(16) _Float16 PT[8][2048];  // per-wave P^T [q 32][key 64]
  // XCD-chunked: 64 consecutive flat ids (16 bh pairs) per XCD (T1)
  const int id = blockIdx.x;
  const int flat = (id & 7) * 64 + (id >> 3);
  const int qb = flat & 3, bh = flat >> 2;
  const int b = bh >> 3, h = bh & 7;
  const int t = threadIdx.x, lane = t & 63, w = t >> 6;
  const int lr = lane & 15, lk = lane >> 4;
  const int q0 = qb * 256 + w * 32;
  const _Float16* qp = q + (size_t)bh * 65536;
  const char* kc = (const char*)(k + (size_t)bh * 65536);  // [p][d] rows 128 B
  const char* vc = (const char*)(v + (size_t)bh * 65536);  // [d][p] rows 2048 B
  // staging map: thread t -> row t>>3, 16B chunk (t&7)*16 (covers 8 KB/tile)
  const int srow = t >> 3, scol = (t & 7) * 16;
  const int sdst = srow * 128 + (scol ^ ((srow & 7) << 4));
  // ---- loop-invariant swizzled LDS byte offsets ----
  int koff[4][2];
#pragma unroll
  for (int j = 0; j < 4; j++) {
    const int row = j * 16 + lr, sw = (row & 7) << 4;
    koff[j][0] = row * 128 + ((lk * 16) ^ sw);
    koff[j][1] = row * 128 + ((64 + lk * 16) ^ sw);
  }
  int pwoff[2][4];  // P-write: q-row g*16+lr, key group j
#pragma unroll
  for (int g = 0; g < 2; g++) {
    const int qhat = g * 16 + lr, sw = (qhat & 7) << 4;
#pragma unroll
    for (int j = 0; j < 4; j++)
      pwoff[g][j] = qhat * 128 + ((j * 32 + lk * 8) ^ sw);
  }
  // Q fragments
  half8 qf[2][2];
#pragma unroll
  for (int g = 0; g < 2; g++)
#pragma unroll
    for (int kk = 0; kk < 2; kk++)
      qf[g][kk] = *(const half8*)(qp + (q0 + g * 16 + lr) * 64 + kk * 32 + lk * 8);
  const half8 onesv = {(_Float16)1.f, (_Float16)1.f, (_Float16)1.f, (_Float16)1.f,
                       (_Float16)1.f, (_Float16)1.f, (_Float16)1.f, (_Float16)1.f};
  // prologue: stage tile 0
  {
    uint4 k0 = *(const uint4*)(kc + srow * 128 + scol);
    uint4 v0 = *(const uint4*)(vc + srow * 2048 + scol);
    *(uint4*)((char*)KT + sdst) = k0;
    *(uint4*)((char*)VT + sdst) = v0;
  }
  __syncthreads();
  f32x4 aco[2][4] = {};
  f32x4 lacc[2] = {};  // row-sum of P via MFMA(P, ones); PV-accumulator layout
  char* Pc = (char*)PT + w * 4096;
#pragma unroll 1
  for (int kt = 0; kt < 16; kt++) {
    const int cur = kt & 1;
    const char* Kc = (const char*)KT + cur * 8192;
    const char* Vc = (const char*)VT + cur * 8192;
    // T14 issue-early: next tile global loads in flight during compute
    uint4 kn, vn;
    if (kt < 15) {
      kn = *(const uint4*)(kc + (kt + 1) * 8192 + srow * 128 + scol);
      vn = *(const uint4*)(vc + srow * 2048 + (kt + 1) * 128 + scol);
    }
    // ---- QK^T swapped, C-init = -10 (softmax offset folded in) ----
    f32x4 s[2][4];
#pragma unroll
    for (int g = 0; g < 2; g++)
#pragma unroll
      for (int j = 0; j < 4; j++) {
        s[g][j][0] = -10.f; s[g][j][1] = -10.f;
        s[g][j][2] = -10.f; s[g][j][3] = -10.f;
      }
    __builtin_amdgcn_s_setprio(1);
#pragma unroll
    for (int j = 0; j < 4; j++) {
      const half8 kf0 = *(const half8*)(Kc + koff[j][0]);
      const half8 kf1 = *(const half8*)(Kc + koff[j][1]);
#pragma unroll
      for (int g = 0; g < 2; g++) {
        s[g][j] = __builtin_amdgcn_mfma_f32_16x16x32_f16(kf0, qf[g][0], s[g][j], 0, 0, 0);
        s[g][j] = __builtin_amdgcn_mfma_f32_16x16x32_f16(kf1, qf[g][1], s[g][j], 0, 0, 0);
      }
    }
    __builtin_amdgcn_s_setprio(0);
    // ---- P = 2^s via raw v_exp_f32, packed store to fp16 LDS tile ----
#pragma unroll
    for (int g = 0; g < 2; g++) {
#pragma unroll
      for (int j = 0; j < 4; j++) {
        uint2 pw;
        pw.x = pk2(__builtin_amdgcn_exp2f(s[g][j][0]),
                   __builtin_amdgcn_exp2f(s[g][j][1]));
        pw.y = pk2(__builtin_amdgcn_exp2f(s[g][j][2]),
                   __builtin_amdgcn_exp2f(s[g][j][3]));
        *(uint2*)(Pc + pwoff[g][j]) = pw;
      }
    }
    // ---- PV: O += P^T * V^T ; l-sum via MFMA(P, ones) ----
    __builtin_amdgcn_s_setprio(1);
#pragma unroll
    for (int kk = 0; kk < 2; kk++) {
      half8 vf[4];
#pragma unroll
      for (int jd = 0; jd < 4; jd++)
        vf[jd] = *(const half8*)(Vc + koff[jd][kk]);
#pragma unroll
      for (int g = 0; g < 2; g++) {
        const half8 pf = *(const half8*)(Pc + koff[g][kk]);
        lacc[g] = __builtin_amdgcn_mfma_f32_16x16x32_f16(pf, onesv, lacc[g], 0, 0, 0);
#pragma unroll
        for (int jd = 0; jd < 4; jd++)
          aco[g][jd] = __builtin_amdgcn_mfma_f32_16x16x32_f16(pf, vf[jd], aco[g][jd], 0, 0, 0);
      }
    }
    __builtin_amdgcn_s_setprio(0);
    // ---- write staged tile, flip buffers ----
    if (kt < 15) {
      *(uint4*)((char*)KT + (cur ^ 1) * 8192 + sdst) = kn;
      *(uint4*)((char*)VT + (cur ^ 1) * 8192 + sdst) = vn;
    }
    __syncthreads();
  }
  // ---- epilogue: divide by l (already in PV layout), store [b,p,c] ----
#pragma unroll
  for (int g = 0; g < 2; g++)
#pragma unroll
    for (int r = 0; r < 4; r++) {
      const float rl = 1.f / lacc[g][r];
      const int row = q0 + g * 16 + 4 * lk + r;
#pragma unroll
      for (int jd = 0; jd < 4; jd++)
        o[((size_t)b * 1024 + row) * 512 + h * 64 + jd * 16 + lr] =
            (_Float16)(aco[g][jd][r] * rl);
    }
}

extern "C" void kernel_launch(void* const* d_in, const int* in_sizes, int n_in,
                              void* d_out, int out_size, void* d_ws, size_t ws_size,
                              hipStream_t stream) {
  const float* x = (const float*)d_in[0];
  const float* gsc = (const float*)d_in[1];
  const float* gbi = (const float*)d_in[2];
  const float* wqkv = (const float*)d_in[3];
  const float* bqkv = (const float*)d_in[4];
  const float* wproj = (const float*)d_in[5];
  const float* bproj = (const float*)d_in[6];
  float* out = (float*)d_out;
  char* ws = (char*)d_ws;
  // workspace layout (bytes)
  float* mr = (float*)ws;                                 // 256*2*4   = 2 KB
  _Float16* wq16 = (_Float16*)(ws + 4096);                // 1536*512*2
  _Float16* wp16 = (_Float16*)(ws + 4096 + 1572864);      // 512*512*2
  _Float16* hn = (_Float16*)(ws + 2101248);               // 16*1024*512*2 (reused for attn out)
  _Float16* q16 = (_Float16*)(ws + 18878464);             // 16*8*1024*64*2
  _Float16* k16 = (_Float16*)(ws + 35655680);
  _Float16* v16 = (_Float16*)(ws + 52432896);             // end ~66 MB

  hipLaunchKernelGGL(prep, dim3(1024), dim3(256), 0, stream, wqkv, wproj, wq16,
                     wp16, x, mr);
  hipLaunchKernelGGL(gn_apply, dim3(16, 8, 16), dim3(256), 0, stream, x, mr, gsc,
                     gbi, hn);
  hipLaunchKernelGGL((gemm_mfma<0>), dim3(8, 12, 16), dim3(512), 0, stream, wq16,
                     hn, bqkv, (const float*)nullptr, (float*)nullptr, q16, k16,
                     v16);
  hipLaunchKernelGGL(attn, dim3(512), dim3(512), 0, stream, q16, k16, v16, hn);
  hipLaunchKernelGGL((gemm_mfma<1>), dim3(8, 4, 16), dim3(512), 0, stream, wp16,
                     hn, bproj, x, out, (_Float16*)nullptr, (_Float16*)nullptr,
                     (_Float16*)nullptr);
}

// Round 19
// 127.232 us; speedup vs baseline: 1.7147x; 1.0059x over previous
//
#include <hip/hip_runtime.h>

typedef _Float16 half8 __attribute__((ext_vector_type(8)));
typedef _Float16 half4 __attribute__((ext_vector_type(4)));
typedef float f32x4 __attribute__((ext_vector_type(4)));

__device__ inline unsigned short f2h(float f) {
  union { _Float16 h; unsigned short u; } cv;
  cv.h = (_Float16)f;
  return cv.u;
}

__device__ inline unsigned int pk2(float a, float b) {
  return __builtin_bit_cast(unsigned int, __builtin_amdgcn_cvt_pkrtz(a, b));
}

// async global->LDS, 16B per lane; LDS dest is wave-uniform base + lane*16
__device__ inline void gload_lds16(const void* g, void* l) {
  __builtin_amdgcn_global_load_lds(
      (const __attribute__((address_space(1))) void*)g,
      (__attribute__((address_space(3))) void*)l, 16, 0, 0);
}

// ---- prep: weights fp32->fp16 via float4 (blocks 0..767) + GN partial stats ----
__global__ __launch_bounds__(256) void prep(const float* __restrict__ wqkv,
                                            const float* __restrict__ wproj,
                                            _Float16* __restrict__ wq,
                                            _Float16* __restrict__ wp,
                                            const float* __restrict__ x,
                                            float* __restrict__ mr) {
  if (blockIdx.x < 768) {
    const int i = blockIdx.x * 256 + threadIdx.x;  // float4 idx, covers 196608
    const float4 v = ((const float4*)wqkv)[i];
    ushort4 pk;
    pk.x = f2h(v.x); pk.y = f2h(v.y); pk.z = f2h(v.z); pk.w = f2h(v.w);
    *(ushort4*)(wq + (size_t)i * 4) = pk;
    if (i < 65536) {
      const float4 u = ((const float4*)wproj)[i];
      ushort4 pu;
      pu.x = f2h(u.x); pu.y = f2h(u.y); pu.z = f2h(u.z); pu.w = f2h(u.w);
      *(ushort4*)(wp + (size_t)i * 4) = pu;
    }
    return;
  }
  const int sb = blockIdx.x - 768;  // 0..255, one per (b,g,half-slab)
  const float4* xv = (const float4*)(x + (size_t)sb * 32768);
  float s = 0.f, s2 = 0.f;
  for (int i = threadIdx.x; i < 8192; i += 256) {
    float4 v = xv[i];
    s += v.x + v.y + v.z + v.w;
    s2 += v.x * v.x + v.y * v.y + v.z * v.z + v.w * v.w;
  }
  for (int m = 32; m; m >>= 1) {
    s += __shfl_down(s, m);
    s2 += __shfl_down(s2, m);
  }
  __shared__ float ls[4], ls2[4];
  const int wid = threadIdx.x >> 6;
  if ((threadIdx.x & 63) == 0) { ls[wid] = s; ls2[wid] = s2; }
  __syncthreads();
  if (threadIdx.x == 0) {
    mr[sb * 2] = ls[0] + ls[1] + ls[2] + ls[3];
    mr[sb * 2 + 1] = ls2[0] + ls2[1] + ls2[2] + ls2[3];
  }
}

// ------- GN apply + transpose: x[b,c,p] -> hn[b,p,c] fp16 (c contiguous) -------
__global__ __launch_bounds__(256) void gn_apply(const float* __restrict__ x,
                                                const float* __restrict__ mr,
                                                const float* __restrict__ sc,
                                                const float* __restrict__ bi,
                                                _Float16* __restrict__ hn) {
  __shared__ __align__(16) _Float16 t[64][72];  // 64p x 64c tile, padded rows
  const int b = blockIdx.z, cb = blockIdx.y, pb = blockIdx.x;
  const int c0 = cb * 64, p0 = pb * 64;
  const int bg = b * 8 + cb;  // group == cb (64 ch per group)
  const float S = mr[bg * 4 + 0] + mr[bg * 4 + 2];
  const float S2 = mr[bg * 4 + 1] + mr[bg * 4 + 3];
  const float mean = S * (1.f / 65536.f);
  const float var = S2 * (1.f / 65536.f) - mean * mean;
  const float rstd = rsqrtf(var + 1e-5f);
  const int tp = threadIdx.x & 63;
  const int tc = threadIdx.x >> 6;
#pragma unroll
  for (int i = 0; i < 16; i++) {
    const int c = tc * 16 + i;
    const float g = sc[c0 + c] * rstd;
    const float v = x[((size_t)b * 512 + c0 + c) * 1024 + p0 + tp];
    t[tp][c] = (_Float16)((v - mean) * g + bi[c0 + c]);
  }
  __syncthreads();
  const int wp = threadIdx.x >> 2;
  const int wc = (threadIdx.x & 3) * 16;
  _Float16* dst = hn + ((size_t)b * 1024 + p0 + wp) * 512 + c0 + wc;
  *(uint4*)dst = *(const uint4*)&t[wp][wc];
  *(uint4*)(dst + 8) = *(const uint4*)&t[wp][wc + 8];
}

// ---- MFMA GEMM: C[o,p] = sum_c A[o,c]*Bt[p,c], 128x128x64 tiles, 8 waves ----
// T4 counted-vmcnt pipeline (m201/HK pattern): double-buffered LDS; stage for
// tile k+2 issued after the post-compute barrier; `s_waitcnt vmcnt(4)` + raw
// s_barrier drains only the PREVIOUS iteration's loads (full compute phase to
// land) instead of __syncthreads()'s vmcnt(0) drain of the fresh ones.
// EPI=0: qkv epilogue (bias, split into q[b,h,p,d](*0.125*log2e), k, v[b,h,d,p])
// EPI=1: proj epilogue (bias + residual, fp32 out [b,c,p])
template <int EPI>
__global__ __launch_bounds__(512, 4) void gemm_mfma(
    const _Float16* __restrict__ A, const _Float16* __restrict__ Bt,
    const float* __restrict__ bias, const float* __restrict__ xin,
    float* __restrict__ fout, _Float16* __restrict__ qo,
    _Float16* __restrict__ ko, _Float16* __restrict__ vo) {
  __shared__ __align__(16) _Float16 As[2][128 * 64];
  __shared__ __align__(16) _Float16 Bs[2][128 * 64];
  const int b = blockIdx.z;
  const int m0 = blockIdx.y * 128, n0 = blockIdx.x * 128;
  const char* Ab = (const char*)A;
  const char* Bb = (const char*)(Bt + (size_t)b * 1024 * 512);
  const int t = threadIdx.x, lane = t & 63, w = t >> 6;
  const int wm = (w & 1) * 64, wn = (w >> 1) * 32;  // 2x4 grid of 64x32
  const int lr = lane & 15, lk = lane >> 4;
  // staging: 512 threads x 2 chunks of 16B cover each 16 KB tile
  int srow[2], scb[2];
#pragma unroll
  for (int it = 0; it < 2; it++) {
    srow[it] = it * 64 + (t >> 3);
    scb[it] = ((t & 7) * 16) ^ ((srow[it] & 7) << 4);
  }
  f32x4 acc[4][2] = {};
  // prologue: stage tiles 0 and 1 (8 gload_lds outstanding/thread)
#pragma unroll
  for (int kp = 0; kp < 2; kp++) {
#pragma unroll
    for (int it = 0; it < 2; it++) {
      const size_t go = (size_t)(m0 + srow[it]) * 1024 + kp * 128 + scb[it];
      const size_t gob = (size_t)(n0 + srow[it]) * 1024 + kp * 128 + scb[it];
      gload_lds16(Ab + go, (char*)As[kp] + it * 8192 + w * 1024);
      gload_lds16(Bb + gob, (char*)Bs[kp] + it * 8192 + w * 1024);
    }
  }
  asm volatile("s_waitcnt vmcnt(4)" ::: "memory");  // tile 0 landed
  __builtin_amdgcn_s_barrier();
  asm volatile("" ::: "memory");
#pragma unroll 1
  for (int ks = 0; ks < 8; ks++) {
    const int cur = ks & 1;
    // compute on buffer cur (ds_read results consumed by MFMA -> lgkm drained)
#pragma unroll
    for (int kk = 0; kk < 2; kk++) {
      half8 af[4], bf[2];
#pragma unroll
      for (int i = 0; i < 4; i++) {
        const int ra = wm + i * 16 + lr;
        af[i] = *(const half8*)((const char*)As[cur] +
                                ((ra * 128 + kk * 64 + lk * 16) ^ ((ra & 7) << 4)));
      }
#pragma unroll
      for (int j = 0; j < 2; j++) {
        const int rb = wn + j * 16 + lr;
        bf[j] = *(const half8*)((const char*)Bs[cur] +
                                ((rb * 128 + kk * 64 + lk * 16) ^ ((rb & 7) << 4)));
      }
#pragma unroll
      for (int i = 0; i < 4; i++)
#pragma unroll
        for (int j = 0; j < 2; j++)
          acc[i][j] = __builtin_amdgcn_mfma_f32_16x16x32_f16(af[i], bf[j],
                                                             acc[i][j], 0, 0, 0);
    }
    if (ks == 7) break;
    asm volatile("" ::: "memory");
    __builtin_amdgcn_s_barrier();  // all waves done reading buf[cur]
    asm volatile("" ::: "memory");
    if (ks + 2 < 8) {
      // restage buf[cur] with tile ks+2; loads span the next compute phase
#pragma unroll
      for (int it = 0; it < 2; it++) {
        const size_t go =
            (size_t)(m0 + srow[it]) * 1024 + (ks + 2) * 128 + scb[it];
        const size_t gob =
            (size_t)(n0 + srow[it]) * 1024 + (ks + 2) * 128 + scb[it];
        gload_lds16(Ab + go, (char*)As[cur] + it * 8192 + w * 1024);
        gload_lds16(Bb + gob, (char*)Bs[cur] + it * 8192 + w * 1024);
      }
      asm volatile("s_waitcnt vmcnt(4)" ::: "memory");  // prev tile landed
    } else {
      asm volatile("s_waitcnt vmcnt(0)" ::: "memory");  // last tile landed
    }
    __builtin_amdgcn_s_barrier();
    asm volatile("" ::: "memory");
  }
#pragma unroll
  for (int i = 0; i < 4; i++) {
    const int o = m0 + wm + i * 16 + lk * 4;  // 4 consecutive rows o..o+3
#pragma unroll
    for (int j = 0; j < 2; j++) {
      const int p = n0 + wn + j * 16 + lr;
      float vv[4];
#pragma unroll
      for (int r = 0; r < 4; r++) vv[r] = acc[i][j][r] + bias[o + r];
      if (EPI == 0) {
        const int sec = o >> 9, oc = o & 511;
        const int h = oc >> 6, d0 = oc & 63;
        if (sec == 0) {  // Q, pre-scaled by 1/sqrt(64) * log2(e)
          const float qs = 0.125f * 1.44269504f;
          ushort4 pk;
          pk.x = f2h(vv[0] * qs); pk.y = f2h(vv[1] * qs);
          pk.z = f2h(vv[2] * qs); pk.w = f2h(vv[3] * qs);
          *(ushort4*)(qo + ((size_t)(b * 8 + h) * 1024 + p) * 64 + d0) = pk;
        } else if (sec == 1) {  // K
          ushort4 pk;
          pk.x = f2h(vv[0]); pk.y = f2h(vv[1]);
          pk.z = f2h(vv[2]); pk.w = f2h(vv[3]);
          *(ushort4*)(ko + ((size_t)(b * 8 + h) * 1024 + p) * 64 + d0) = pk;
        } else {  // V, transposed to [d, p]
#pragma unroll
          for (int r = 0; r < 4; r++)
            vo[((size_t)(b * 8 + h) * 64 + d0 + r) * 1024 + p] = (_Float16)vv[r];
        }
      } else {
        const size_t idx = ((size_t)b * 512 + o) * 1024 + p;
#pragma unroll
        for (int r = 0; r < 4; r++)
          fout[idx + (size_t)r * 1024] = xin[idx + (size_t)r * 1024] + vv[r];
      }
    }
  }
}

// ---- flash attention v7s: fixed-offset softmax, raw v_exp_f32, MFMA l-sum ----
// block = (b,h) x 256 q-rows (8 waves x 32); q pre-scaled by 0.125*log2e
// P = 2^(s-10) via s initialized at -10; l = sum P via MFMA
// k [b,h,p,d]; v [b,h,d,p]; o [b,p,c] fp16
__global__ __launch_bounds__(512, 4) void attn(const _Float16* __restrict__ q,
                                               const _Float16* __restrict__ k,
                                               const _Float16* __restrict__ v,
                                               _Float16* __restrict__ o) {
  __shared__ __align__(16) _Float16 KT[2][4096];  // [buf][key 64][d 64] swizzled
  __shared__ __align__(16) _Float16 VT[2][4096];  // [buf][d 64][key 64] swizzled
  __shared__ __align__(16) _Float16 PT[8][2048];  // per-wave P^T [q 32][key 64]
  // XCD-chunked: 64 consecutive flat ids (16 bh pairs) per XCD (T1)
  const int id = blockIdx.x;
  const int flat = (id & 7) * 64 + (id >> 3);
  const int qb = flat & 3, bh = flat >> 2;
  const int b = bh >> 3, h = bh & 7;
  const int t = threadIdx.x, lane = t & 63, w = t >> 6;
  const int lr = lane & 15, lk = lane >> 4;
  const int q0 = qb * 256 + w * 32;
  const _Float16* qp = q + (size_t)bh * 65536;
  const char* kc = (const char*)(k + (size_t)bh * 65536);  // [p][d] rows 128 B
  const char* vc = (const char*)(v + (size_t)bh * 65536);  // [d][p] rows 2048 B
  // staging map: thread t -> row t>>3, 16B chunk (t&7)*16 (covers 8 KB/tile)
  const int srow = t >> 3, scol = (t & 7) * 16;
  const int sdst = srow * 128 + (scol ^ ((srow & 7) << 4));
  // ---- loop-invariant swizzled LDS byte offsets ----
  int koff[4][2];
#pragma unroll
  for (int j = 0; j < 4; j++) {
    const int row = j * 16 + lr, sw = (row & 7) << 4;
    koff[j][0] = row * 128 + ((lk * 16) ^ sw);
    koff[j][1] = row * 128 + ((64 + lk * 16) ^ sw);
  }
  int pwoff[2][4];  // P-write: q-row g*16+lr, key group j
#pragma unroll
  for (int g = 0; g < 2; g++) {
    const int qhat = g * 16 + lr, sw = (qhat & 7) << 4;
#pragma unroll
    for (int j = 0; j < 4; j++)
      pwoff[g][j] = qhat * 128 + ((j * 32 + lk * 8) ^ sw);
  }
  // Q fragments
  half8 qf[2][2];
#pragma unroll
  for (int g = 0; g < 2; g++)
#pragma unroll
    for (int kk = 0; kk < 2; kk++)
      qf[g][kk] = *(const half8*)(qp + (q0 + g * 16 + lr) * 64 + kk * 32 + lk * 8);
  const half8 onesv = {(_Float16)1.f, (_Float16)1.f, (_Float16)1.f, (_Float16)1.f,
                       (_Float16)1.f, (_Float16)1.f, (_Float16)1.f, (_Float16)1.f};
  // prologue: stage tile 0
  {
    uint4 k0 = *(const uint4*)(kc + srow * 128 + scol);
    uint4 v0 = *(const uint4*)(vc + srow * 2048 + scol);
    *(uint4*)((char*)KT + sdst) = k0;
    *(uint4*)((char*)VT + sdst) = v0;
  }
  __syncthreads();
  f32x4 aco[2][4] = {};
  f32x4 lacc[2] = {};  // row-sum of P via MFMA(P, ones); PV-accumulator layout
  char* Pc = (char*)PT + w * 4096;
#pragma unroll 1
  for (int kt = 0; kt < 16; kt++) {
    const int cur = kt & 1;
    const char* Kc = (const char*)KT + cur * 8192;
    const char* Vc = (const char*)VT + cur * 8192;
    // T14 issue-early: next tile global loads in flight during compute
    uint4 kn, vn;
    if (kt < 15) {
      kn = *(const uint4*)(kc + (kt + 1) * 8192 + srow * 128 + scol);
      vn = *(const uint4*)(vc + srow * 2048 + (kt + 1) * 128 + scol);
    }
    // ---- QK^T swapped, C-init = -10 (softmax offset folded in) ----
    f32x4 s[2][4];
#pragma unroll
    for (int g = 0; g < 2; g++)
#pragma unroll
      for (int j = 0; j < 4; j++) {
        s[g][j][0] = -10.f; s[g][j][1] = -10.f;
        s[g][j][2] = -10.f; s[g][j][3] = -10.f;
      }
    __builtin_amdgcn_s_setprio(1);
#pragma unroll
    for (int j = 0; j < 4; j++) {
      const half8 kf0 = *(const half8*)(Kc + koff[j][0]);
      const half8 kf1 = *(const half8*)(Kc + koff[j][1]);
#pragma unroll
      for (int g = 0; g < 2; g++) {
        s[g][j] = __builtin_amdgcn_mfma_f32_16x16x32_f16(kf0, qf[g][0], s[g][j], 0, 0, 0);
        s[g][j] = __builtin_amdgcn_mfma_f32_16x16x32_f16(kf1, qf[g][1], s[g][j], 0, 0, 0);
      }
    }
    __builtin_amdgcn_s_setprio(0);
    // ---- P = 2^s via raw v_exp_f32, packed store to fp16 LDS tile ----
#pragma unroll
    for (int g = 0; g < 2; g++) {
#pragma unroll
      for (int j = 0; j < 4; j++) {
        uint2 pw;
        pw.x = pk2(__builtin_amdgcn_exp2f(s[g][j][0]),
                   __builtin_amdgcn_exp2f(s[g][j][1]));
        pw.y = pk2(__builtin_amdgcn_exp2f(s[g][j][2]),
                   __builtin_amdgcn_exp2f(s[g][j][3]));
        *(uint2*)(Pc + pwoff[g][j]) = pw;
      }
    }
    // ---- PV: O += P^T * V^T ; l-sum via MFMA(P, ones) ----
    __builtin_amdgcn_s_setprio(1);
#pragma unroll
    for (int kk = 0; kk < 2; kk++) {
      half8 vf[4];
#pragma unroll
      for (int jd = 0; jd < 4; jd++)
        vf[jd] = *(const half8*)(Vc + koff[jd][kk]);
#pragma unroll
      for (int g = 0; g < 2; g++) {
        const half8 pf = *(const half8*)(Pc + koff[g][kk]);
        lacc[g] = __builtin_amdgcn_mfma_f32_16x16x32_f16(pf, onesv, lacc[g], 0, 0, 0);
#pragma unroll
        for (int jd = 0; jd < 4; jd++)
          aco[g][jd] = __builtin_amdgcn_mfma_f32_16x16x32_f16(pf, vf[jd], aco[g][jd], 0, 0, 0);
      }
    }
    __builtin_amdgcn_s_setprio(0);
    // ---- write staged tile, flip buffers ----
    if (kt < 15) {
      *(uint4*)((char*)KT + (cur ^ 1) * 8192 + sdst) = kn;
      *(uint4*)((char*)VT + (cur ^ 1) * 8192 + sdst) = vn;
    }
    __syncthreads();
  }
  // ---- epilogue: divide by l (already in PV layout), store [b,p,c] ----
#pragma unroll
  for (int g = 0; g < 2; g++)
#pragma unroll
    for (int r = 0; r < 4; r++) {
      const float rl = 1.f / lacc[g][r];
      const int row = q0 + g * 16 + 4 * lk + r;
#pragma unroll
      for (int jd = 0; jd < 4; jd++)
        o[((size_t)b * 1024 + row) * 512 + h * 64 + jd * 16 + lr] =
            (_Float16)(aco[g][jd][r] * rl);
    }
}

extern "C" void kernel_launch(void* const* d_in, const int* in_sizes, int n_in,
                              void* d_out, int out_size, void* d_ws, size_t ws_size,
                              hipStream_t stream) {
  const float* x = (const float*)d_in[0];
  const float* gsc = (const float*)d_in[1];
  const float* gbi = (const float*)d_in[2];
  const float* wqkv = (const float*)d_in[3];
  const float* bqkv = (const float*)d_in[4];
  const float* wproj = (const float*)d_in[5];
  const float* bproj = (const float*)d_in[6];
  float* out = (float*)d_out;
  char* ws = (char*)d_ws;
  // workspace layout (bytes)
  float* mr = (float*)ws;                                 // 256*2*4   = 2 KB
  _Float16* wq16 = (_Float16*)(ws + 4096);                // 1536*512*2
  _Float16* wp16 = (_Float16*)(ws + 4096 + 1572864);      // 512*512*2
  _Float16* hn = (_Float16*)(ws + 2101248);               // 16*1024*512*2 (reused for attn out)
  _Float16* q16 = (_Float16*)(ws + 18878464);             // 16*8*1024*64*2
  _Float16* k16 = (_Float16*)(ws + 35655680);
  _Float16* v16 = (_Float16*)(ws + 52432896);             // end ~66 MB

  hipLaunchKernelGGL(prep, dim3(1024), dim3(256), 0, stream, wqkv, wproj, wq16,
                     wp16, x, mr);
  hipLaunchKernelGGL(gn_apply, dim3(16, 8, 16), dim3(256), 0, stream, x, mr, gsc,
                     gbi, hn);
  hipLaunchKernelGGL((gemm_mfma<0>), dim3(8, 12, 16), dim3(512), 0, stream, wq16,
                     hn, bqkv, (const float*)nullptr, (float*)nullptr, q16, k16,
                     v16);
  hipLaunchKernelGGL(attn, dim3(512), dim3(512), 0, stream, q16, k16, v16, hn);
  hipLaunchKernelGGL((gemm_mfma<1>), dim3(8, 4, 16), dim3(512), 0, stream, wp16,
                     hn, bproj, x, out, (_Float16*)nullptr, (_Float16*)nullptr,
                     (_Float16*)nullptr);
}

// Round 20
// 127.181 us; speedup vs baseline: 1.7154x; 1.0004x over previous
//
#include <hip/hip_runtime.h>

typedef _Float16 half8 __attribute__((ext_vector_type(8)));
typedef _Float16 half4 __attribute__((ext_vector_type(4)));
typedef float f32x4 __attribute__((ext_vector_type(4)));

__device__ inline unsigned short f2h(float f) {
  union { _Float16 h; unsigned short u; } cv;
  cv.h = (_Float16)f;
  return cv.u;
}

__device__ inline unsigned int pk2(float a, float b) {
  return __builtin_bit_cast(unsigned int, __builtin_amdgcn_cvt_pkrtz(a, b));
}

// async global->LDS, 16B per lane; LDS dest is wave-uniform base + lane*16
__device__ inline void gload_lds16(const void* g, void* l) {
  __builtin_amdgcn_global_load_lds(
      (const __attribute__((address_space(1))) void*)g,
      (__attribute__((address_space(3))) void*)l, 16, 0, 0);
}

// ---- prep: weights fp32->fp16 via float4 (blocks 0..767) + GN partial stats ----
__global__ __launch_bounds__(256) void prep(const float* __restrict__ wqkv,
                                            const float* __restrict__ wproj,
                                            _Float16* __restrict__ wq,
                                            _Float16* __restrict__ wp,
                                            const float* __restrict__ x,
                                            float* __restrict__ mr) {
  if (blockIdx.x < 768) {
    const int i = blockIdx.x * 256 + threadIdx.x;  // float4 idx, covers 196608
    const float4 v = ((const float4*)wqkv)[i];
    ushort4 pk;
    pk.x = f2h(v.x); pk.y = f2h(v.y); pk.z = f2h(v.z); pk.w = f2h(v.w);
    *(ushort4*)(wq + (size_t)i * 4) = pk;
    if (i < 65536) {
      const float4 u = ((const float4*)wproj)[i];
      ushort4 pu;
      pu.x = f2h(u.x); pu.y = f2h(u.y); pu.z = f2h(u.z); pu.w = f2h(u.w);
      *(ushort4*)(wp + (size_t)i * 4) = pu;
    }
    return;
  }
  const int sb = blockIdx.x - 768;  // 0..255, one per (b,g,half-slab)
  const float4* xv = (const float4*)(x + (size_t)sb * 32768);
  float s = 0.f, s2 = 0.f;
  for (int i = threadIdx.x; i < 8192; i += 256) {
    float4 v = xv[i];
    s += v.x + v.y + v.z + v.w;
    s2 += v.x * v.x + v.y * v.y + v.z * v.z + v.w * v.w;
  }
  for (int m = 32; m; m >>= 1) {
    s += __shfl_down(s, m);
    s2 += __shfl_down(s2, m);
  }
  __shared__ float ls[4], ls2[4];
  const int wid = threadIdx.x >> 6;
  if ((threadIdx.x & 63) == 0) { ls[wid] = s; ls2[wid] = s2; }
  __syncthreads();
  if (threadIdx.x == 0) {
    mr[sb * 2] = ls[0] + ls[1] + ls[2] + ls[3];
    mr[sb * 2 + 1] = ls2[0] + ls2[1] + ls2[2] + ls2[3];
  }
}

// ------- GN apply + transpose: x[b,c,p] -> hn[b,p,c] fp16 (c contiguous) -------
__global__ __launch_bounds__(256) void gn_apply(const float* __restrict__ x,
                                                const float* __restrict__ mr,
                                                const float* __restrict__ sc,
                                                const float* __restrict__ bi,
                                                _Float16* __restrict__ hn) {
  __shared__ __align__(16) _Float16 t[64][72];  // 64p x 64c tile, padded rows
  const int b = blockIdx.z, cb = blockIdx.y, pb = blockIdx.x;
  const int c0 = cb * 64, p0 = pb * 64;
  const int bg = b * 8 + cb;  // group == cb (64 ch per group)
  const float S = mr[bg * 4 + 0] + mr[bg * 4 + 2];
  const float S2 = mr[bg * 4 + 1] + mr[bg * 4 + 3];
  const float mean = S * (1.f / 65536.f);
  const float var = S2 * (1.f / 65536.f) - mean * mean;
  const float rstd = rsqrtf(var + 1e-5f);
  const int tp = threadIdx.x & 63;
  const int tc = threadIdx.x >> 6;
#pragma unroll
  for (int i = 0; i < 16; i++) {
    const int c = tc * 16 + i;
    const float g = sc[c0 + c] * rstd;
    const float v = x[((size_t)b * 512 + c0 + c) * 1024 + p0 + tp];
    t[tp][c] = (_Float16)((v - mean) * g + bi[c0 + c]);
  }
  __syncthreads();
  const int wp = threadIdx.x >> 2;
  const int wc = (threadIdx.x & 3) * 16;
  _Float16* dst = hn + ((size_t)b * 1024 + p0 + wp) * 512 + c0 + wc;
  *(uint4*)dst = *(const uint4*)&t[wp][wc];
  *(uint4*)(dst + 8) = *(const uint4*)&t[wp][wc + 8];
}

// ---- MFMA GEMM: C[o,p] = sum_c A[o,c]*Bt[p,c], 128x128x64 tiles, 8 waves ----
// T4 counted-vmcnt pipeline + T1 XCD-chunked 1-D grid: each XCD owns a
// contiguous run of logical tiles (= 2 complete batches -> A + B panels fit
// its 4 MB L2; kills the 2x cross-XCD over-fetch seen as FETCH=19 MB).
// EPI=0: qkv epilogue (bias, split into q[b,h,p,d](*0.125*log2e), k, v[b,h,d,p])
// EPI=1: proj epilogue (bias + residual, fp32 out [b,c,p])
template <int EPI>
__global__ __launch_bounds__(512, 4) void gemm_mfma(
    const _Float16* __restrict__ A, const _Float16* __restrict__ Bt,
    const float* __restrict__ bias, const float* __restrict__ xin,
    float* __restrict__ fout, _Float16* __restrict__ qo,
    _Float16* __restrict__ ko, _Float16* __restrict__ vo) {
  __shared__ __align__(16) _Float16 As[2][128 * 64];
  __shared__ __align__(16) _Float16 Bs[2][128 * 64];
  // T1: bijective XCD-chunked decode (grid divisible by 8)
  const int id = blockIdx.x;
  const int cpx = (EPI == 0) ? 192 : 64;  // tiles per XCD (grid/8)
  const int nt = (EPI == 0) ? 96 : 32;    // tiles per batch (12|4 m x 8 n)
  const int logical = (id & 7) * cpx + (id >> 3);
  const int b = logical / nt, rem = logical % nt;
  const int m0 = (rem >> 3) * 128, n0 = (rem & 7) * 128;
  const char* Ab = (const char*)A;
  const char* Bb = (const char*)(Bt + (size_t)b * 1024 * 512);
  const int t = threadIdx.x, lane = t & 63, w = t >> 6;
  const int wm = (w & 1) * 64, wn = (w >> 1) * 32;  // 2x4 grid of 64x32
  const int lr = lane & 15, lk = lane >> 4;
  // staging: 512 threads x 2 chunks of 16B cover each 16 KB tile
  int srow[2], scb[2];
#pragma unroll
  for (int it = 0; it < 2; it++) {
    srow[it] = it * 64 + (t >> 3);
    scb[it] = ((t & 7) * 16) ^ ((srow[it] & 7) << 4);
  }
  f32x4 acc[4][2] = {};
  // prologue: stage tiles 0 and 1 (8 gload_lds outstanding/thread)
#pragma unroll
  for (int kp = 0; kp < 2; kp++) {
#pragma unroll
    for (int it = 0; it < 2; it++) {
      const size_t go = (size_t)(m0 + srow[it]) * 1024 + kp * 128 + scb[it];
      const size_t gob = (size_t)(n0 + srow[it]) * 1024 + kp * 128 + scb[it];
      gload_lds16(Ab + go, (char*)As[kp] + it * 8192 + w * 1024);
      gload_lds16(Bb + gob, (char*)Bs[kp] + it * 8192 + w * 1024);
    }
  }
  asm volatile("s_waitcnt vmcnt(4)" ::: "memory");  // tile 0 landed
  __builtin_amdgcn_s_barrier();
  asm volatile("" ::: "memory");
#pragma unroll 1
  for (int ks = 0; ks < 8; ks++) {
    const int cur = ks & 1;
    // compute on buffer cur (ds_read results consumed by MFMA -> lgkm drained)
#pragma unroll
    for (int kk = 0; kk < 2; kk++) {
      half8 af[4], bf[2];
#pragma unroll
      for (int i = 0; i < 4; i++) {
        const int ra = wm + i * 16 + lr;
        af[i] = *(const half8*)((const char*)As[cur] +
                                ((ra * 128 + kk * 64 + lk * 16) ^ ((ra & 7) << 4)));
      }
#pragma unroll
      for (int j = 0; j < 2; j++) {
        const int rb = wn + j * 16 + lr;
        bf[j] = *(const half8*)((const char*)Bs[cur] +
                                ((rb * 128 + kk * 64 + lk * 16) ^ ((rb & 7) << 4)));
      }
#pragma unroll
      for (int i = 0; i < 4; i++)
#pragma unroll
        for (int j = 0; j < 2; j++)
          acc[i][j] = __builtin_amdgcn_mfma_f32_16x16x32_f16(af[i], bf[j],
                                                             acc[i][j], 0, 0, 0);
    }
    if (ks == 7) break;
    asm volatile("" ::: "memory");
    __builtin_amdgcn_s_barrier();  // all waves done reading buf[cur]
    asm volatile("" ::: "memory");
    if (ks + 2 < 8) {
      // restage buf[cur] with tile ks+2; loads span the next compute phase
#pragma unroll
      for (int it = 0; it < 2; it++) {
        const size_t go =
            (size_t)(m0 + srow[it]) * 1024 + (ks + 2) * 128 + scb[it];
        const size_t gob =
            (size_t)(n0 + srow[it]) * 1024 + (ks + 2) * 128 + scb[it];
        gload_lds16(Ab + go, (char*)As[cur] + it * 8192 + w * 1024);
        gload_lds16(Bb + gob, (char*)Bs[cur] + it * 8192 + w * 1024);
      }
      asm volatile("s_waitcnt vmcnt(4)" ::: "memory");  // prev tile landed
    } else {
      asm volatile("s_waitcnt vmcnt(0)" ::: "memory");  // last tile landed
    }
    __builtin_amdgcn_s_barrier();
    asm volatile("" ::: "memory");
  }
#pragma unroll
  for (int i = 0; i < 4; i++) {
    const int o = m0 + wm + i * 16 + lk * 4;  // 4 consecutive rows o..o+3
#pragma unroll
    for (int j = 0; j < 2; j++) {
      const int p = n0 + wn + j * 16 + lr;
      float vv[4];
#pragma unroll
      for (int r = 0; r < 4; r++) vv[r] = acc[i][j][r] + bias[o + r];
      if (EPI == 0) {
        const int sec = o >> 9, oc = o & 511;
        const int h = oc >> 6, d0 = oc & 63;
        if (sec == 0) {  // Q, pre-scaled by 1/sqrt(64) * log2(e)
          const float qs = 0.125f * 1.44269504f;
          ushort4 pk;
          pk.x = f2h(vv[0] * qs); pk.y = f2h(vv[1] * qs);
          pk.z = f2h(vv[2] * qs); pk.w = f2h(vv[3] * qs);
          *(ushort4*)(qo + ((size_t)(b * 8 + h) * 1024 + p) * 64 + d0) = pk;
        } else if (sec == 1) {  // K
          ushort4 pk;
          pk.x = f2h(vv[0]); pk.y = f2h(vv[1]);
          pk.z = f2h(vv[2]); pk.w = f2h(vv[3]);
          *(ushort4*)(ko + ((size_t)(b * 8 + h) * 1024 + p) * 64 + d0) = pk;
        } else {  // V, transposed to [d, p]
#pragma unroll
          for (int r = 0; r < 4; r++)
            vo[((size_t)(b * 8 + h) * 64 + d0 + r) * 1024 + p] = (_Float16)vv[r];
        }
      } else {
        const size_t idx = ((size_t)b * 512 + o) * 1024 + p;
#pragma unroll
        for (int r = 0; r < 4; r++)
          fout[idx + (size_t)r * 1024] = xin[idx + (size_t)r * 1024] + vv[r];
      }
    }
  }
}

// ---- flash attention v7s: fixed-offset softmax, raw v_exp_f32, MFMA l-sum ----
// block = (b,h) x 256 q-rows (8 waves x 32); q pre-scaled by 0.125*log2e
// P = 2^(s-10) via s initialized at -10; l = sum P via MFMA
// k [b,h,p,d]; v [b,h,d,p]; o [b,p,c] fp16
__global__ __launch_bounds__(512, 4) void attn(const _Float16* __restrict__ q,
                                               const _Float16* __restrict__ k,
                                               const _Float16* __restrict__ v,
                                               _Float16* __restrict__ o) {
  __shared__ __align__(16) _Float16 KT[2][4096];  // [buf][key 64][d 64] swizzled
  __shared__ __align__(16) _Float16 VT[2][4096];  // [buf][d 64][key 64] swizzled
  __shared__ __align__(16) _Float16 PT[8][2048];  // per-wave P^T [q 32][key 64]
  // XCD-chunked: 64 consecutive flat ids (16 bh pairs) per XCD (T1)
  const int id = blockIdx.x;
  const int flat = (id & 7) * 64 + (id >> 3);
  const int qb = flat & 3, bh = flat >> 2;
  const int b = bh >> 3, h = bh & 7;
  const int t = threadIdx.x, lane = t & 63, w = t >> 6;
  const int lr = lane & 15, lk = lane >> 4;
  const int q0 = qb * 256 + w * 32;
  const _Float16* qp = q + (size_t)bh * 65536;
  const char* kc = (const char*)(k + (size_t)bh * 65536);  // [p][d] rows 128 B
  const char* vc = (const char*)(v + (size_t)bh * 65536);  // [d][p] rows 2048 B
  // staging map: thread t -> row t>>3, 16B chunk (t&7)*16 (covers 8 KB/tile)
  const int srow = t >> 3, scol = (t & 7) * 16;
  const int sdst = srow * 128 + (scol ^ ((srow & 7) << 4));
  // ---- loop-invariant swizzled LDS byte offsets ----
  int koff[4][2];
#pragma unroll
  for (int j = 0; j < 4; j++) {
    const int row = j * 16 + lr, sw = (row & 7) << 4;
    koff[j][0] = row * 128 + ((lk * 16) ^ sw);
    koff[j][1] = row * 128 + ((64 + lk * 16) ^ sw);
  }
  int pwoff[2][4];  // P-write: q-row g*16+lr, key group j
#pragma unroll
  for (int g = 0; g < 2; g++) {
    const int qhat = g * 16 + lr, sw = (qhat & 7) << 4;
#pragma unroll
    for (int j = 0; j < 4; j++)
      pwoff[g][j] = qhat * 128 + ((j * 32 + lk * 8) ^ sw);
  }
  // Q fragments
  half8 qf[2][2];
#pragma unroll
  for (int g = 0; g < 2; g++)
#pragma unroll
    for (int kk = 0; kk < 2; kk++)
      qf[g][kk] = *(const half8*)(qp + (q0 + g * 16 + lr) * 64 + kk * 32 + lk * 8);
  const half8 onesv = {(_Float16)1.f, (_Float16)1.f, (_Float16)1.f, (_Float16)1.f,
                       (_Float16)1.f, (_Float16)1.f, (_Float16)1.f, (_Float16)1.f};
  // prologue: stage tile 0
  {
    uint4 k0 = *(const uint4*)(kc + srow * 128 + scol);
    uint4 v0 = *(const uint4*)(vc + srow * 2048 + scol);
    *(uint4*)((char*)KT + sdst) = k0;
    *(uint4*)((char*)VT + sdst) = v0;
  }
  __syncthreads();
  f32x4 aco[2][4] = {};
  f32x4 lacc[2] = {};  // row-sum of P via MFMA(P, ones); PV-accumulator layout
  char* Pc = (char*)PT + w * 4096;
#pragma unroll 1
  for (int kt = 0; kt < 16; kt++) {
    const int cur = kt & 1;
    const char* Kc = (const char*)KT + cur * 8192;
    const char* Vc = (const char*)VT + cur * 8192;
    // T14 issue-early: next tile global loads in flight during compute
    uint4 kn, vn;
    if (kt < 15) {
      kn = *(const uint4*)(kc + (kt + 1) * 8192 + srow * 128 + scol);
      vn = *(const uint4*)(vc + srow * 2048 + (kt + 1) * 128 + scol);
    }
    // ---- QK^T swapped, C-init = -10 (softmax offset folded in) ----
    f32x4 s[2][4];
#pragma unroll
    for (int g = 0; g < 2; g++)
#pragma unroll
      for (int j = 0; j < 4; j++) {
        s[g][j][0] = -10.f; s[g][j][1] = -10.f;
        s[g][j][2] = -10.f; s[g][j][3] = -10.f;
      }
    __builtin_amdgcn_s_setprio(1);
#pragma unroll
    for (int j = 0; j < 4; j++) {
      const half8 kf0 = *(const half8*)(Kc + koff[j][0]);
      const half8 kf1 = *(const half8*)(Kc + koff[j][1]);
#pragma unroll
      for (int g = 0; g < 2; g++) {
        s[g][j] = __builtin_amdgcn_mfma_f32_16x16x32_f16(kf0, qf[g][0], s[g][j], 0, 0, 0);
        s[g][j] = __builtin_amdgcn_mfma_f32_16x16x32_f16(kf1, qf[g][1], s[g][j], 0, 0, 0);
      }
    }
    __builtin_amdgcn_s_setprio(0);
    // ---- P = 2^s via raw v_exp_f32, packed store to fp16 LDS tile ----
#pragma unroll
    for (int g = 0; g < 2; g++) {
#pragma unroll
      for (int j = 0; j < 4; j++) {
        uint2 pw;
        pw.x = pk2(__builtin_amdgcn_exp2f(s[g][j][0]),
                   __builtin_amdgcn_exp2f(s[g][j][1]));
        pw.y = pk2(__builtin_amdgcn_exp2f(s[g][j][2]),
                   __builtin_amdgcn_exp2f(s[g][j][3]));
        *(uint2*)(Pc + pwoff[g][j]) = pw;
      }
    }
    // ---- PV: O += P^T * V^T ; l-sum via MFMA(P, ones) ----
    __builtin_amdgcn_s_setprio(1);
#pragma unroll
    for (int kk = 0; kk < 2; kk++) {
      half8 vf[4];
#pragma unroll
      for (int jd = 0; jd < 4; jd++)
        vf[jd] = *(const half8*)(Vc + koff[jd][kk]);
#pragma unroll
      for (int g = 0; g < 2; g++) {
        const half8 pf = *(const half8*)(Pc + koff[g][kk]);
        lacc[g] = __builtin_amdgcn_mfma_f32_16x16x32_f16(pf, onesv, lacc[g], 0, 0, 0);
#pragma unroll
        for (int jd = 0; jd < 4; jd++)
          aco[g][jd] = __builtin_amdgcn_mfma_f32_16x16x32_f16(pf, vf[jd], aco[g][jd], 0, 0, 0);
      }
    }
    __builtin_amdgcn_s_setprio(0);
    // ---- write staged tile, flip buffers ----
    if (kt < 15) {
      *(uint4*)((char*)KT + (cur ^ 1) * 8192 + sdst) = kn;
      *(uint4*)((char*)VT + (cur ^ 1) * 8192 + sdst) = vn;
    }
    __syncthreads();
  }
  // ---- epilogue: divide by l (already in PV layout), store [b,p,c] ----
#pragma unroll
  for (int g = 0; g < 2; g++)
#pragma unroll
    for (int r = 0; r < 4; r++) {
      const float rl = 1.f / lacc[g][r];
      const int row = q0 + g * 16 + 4 * lk + r;
#pragma unroll
      for (int jd = 0; jd < 4; jd++)
        o[((size_t)b * 1024 + row) * 512 + h * 64 + jd * 16 + lr] =
            (_Float16)(aco[g][jd][r] * rl);
    }
}

extern "C" void kernel_launch(void* const* d_in, const int* in_sizes, int n_in,
                              void* d_out, int out_size, void* d_ws, size_t ws_size,
                              hipStream_t stream) {
  const float* x = (const float*)d_in[0];
  const float* gsc = (const float*)d_in[1];
  const float* gbi = (const float*)d_in[2];
  const float* wqkv = (const float*)d_in[3];
  const float* bqkv = (const float*)d_in[4];
  const float* wproj = (const float*)d_in[5];
  const float* bproj = (const float*)d_in[6];
  float* out = (float*)d_out;
  char* ws = (char*)d_ws;
  // workspace layout (bytes)
  float* mr = (float*)ws;                                 // 256*2*4   = 2 KB
  _Float16* wq16 = (_Float16*)(ws + 4096);                // 1536*512*2
  _Float16* wp16 = (_Float16*)(ws + 4096 + 1572864);      // 512*512*2
  _Float16* hn = (_Float16*)(ws + 2101248);               // 16*1024*512*2 (reused for attn out)
  _Float16* q16 = (_Float16*)(ws + 18878464);             // 16*8*1024*64*2
  _Float16* k16 = (_Float16*)(ws + 35655680);
  _Float16* v16 = (_Float16*)(ws + 52432896);             // end ~66 MB

  hipLaunchKernelGGL(prep, dim3(1024), dim3(256), 0, stream, wqkv, wproj, wq16,
                     wp16, x, mr);
  hipLaunchKernelGGL(gn_apply, dim3(16, 8, 16), dim3(256), 0, stream, x, mr, gsc,
                     gbi, hn);
  hipLaunchKernelGGL((gemm_mfma<0>), dim3(1536), dim3(512), 0, stream, wq16,
                     hn, bqkv, (const float*)nullptr, (float*)nullptr, q16, k16,
                     v16);
  hipLaunchKernelGGL(attn, dim3(512), dim3(512), 0, stream, q16, k16, v16, hn);
  hipLaunchKernelGGL((gemm_mfma<1>), dim3(512), dim3(512), 0, stream, wp16,
                     hn, bproj, x, out, (_Float16*)nullptr, (_Float16*)nullptr,
                     (_Float16*)nullptr);
}